// Round 2
// baseline (7493.397 us; speedup 1.0000x reference)
//
#include <hip/hip_runtime.h>
#include <hip/hip_bf16.h>
#include <math.h>

typedef __hip_bfloat16 bf16;

#define N_NODES   100000
#define N_EDGES   1600000
#define N_GRAPHS  64
#define OP_EMB_D  32
#define NF_D      140
#define CFG_D     18
#define LIN_IN    190
#define LIN_OUT   128
#define HD        64

__device__ __forceinline__ float b2f(bf16 v) { return __bfloat162float(v); }

// weight-storage helpers: LDS weights may be fp32 or bf16
__device__ __forceinline__ float ldw(float v) { return v; }
__device__ __forceinline__ float ldw(bf16 v)  { return b2f(v); }
__device__ __forceinline__ void  stw(float& d, float v) { d = v; }
__device__ __forceinline__ void  stw(bf16& d, float v)  { d = __float2bfloat16(v); }

// monotone float<->uint encoding for atomicMax on floats
__device__ __forceinline__ unsigned fenc(float f) {
    unsigned u = __float_as_uint(f);
    return (u & 0x80000000u) ? ~u : (u | 0x80000000u);
}
__device__ __forceinline__ float fdec(unsigned u) {
    unsigned v = (u & 0x80000000u) ? (u & 0x7FFFFFFFu) : ~u;
    return __uint_as_float(v);
}

// x0 = relu(concat(node_feat, op_emb[opcode], cfg) @ lin_w + lin_b)  (N,190)@(190,128)
__global__ __launch_bounds__(256) void embed_linear(
    const float* __restrict__ node_feat, const float* __restrict__ cfg,
    const int* __restrict__ opcode, const float* __restrict__ op_emb,
    const float* __restrict__ lin_w, const float* __restrict__ lin_b,
    float* __restrict__ x_out)
{
    __shared__ bf16  sw[LIN_IN * LIN_OUT];   // 48640 B (bf16 storage)
    __shared__ float s_in[2][LIN_IN];
    const int tid = threadIdx.x;
    const int j   = tid & 127;               // output column
    const int sub = tid >> 7;                // node slot 0/1
    for (int i = tid; i < LIN_IN * LIN_OUT; i += 256) stw(sw[i], lin_w[i]);
    const float bias = lin_b[j];
    __syncthreads();
    for (int base = blockIdx.x * 2; base < N_NODES; base += gridDim.x * 2) {
        const int n = base + sub;
        const bool act = (n < N_NODES);
        if (act) {
            for (int i = j; i < NF_D; i += 128) s_in[sub][i] = node_feat[(long long)n * NF_D + i];
            const int op = opcode[n];
            if (j < OP_EMB_D) s_in[sub][NF_D + j] = op_emb[op * OP_EMB_D + j];
            if (j < CFG_D)    s_in[sub][NF_D + OP_EMB_D + j] = cfg[(long long)n * CFG_D + j];
        }
        __syncthreads();
        if (act) {
            float acc = bias;
            #pragma unroll 2
            for (int i = 0; i < LIN_IN; ++i)
                acc += s_in[sub][i] * b2f(sw[i * LIN_OUT + j]);
            x_out[(long long)n * LIN_OUT + j] = fmaxf(acc, 0.0f);
        }
        __syncthreads();
    }
}

__global__ void deg_kernel(const int* __restrict__ dst, float* __restrict__ deg) {
    int e = blockIdx.x * blockDim.x + threadIdx.x;
    if (e < N_EDGES) atomicAdd(&deg[dst[e]], 1.0f);
}

// xp = relu(x @ pw + pb)   (N,D)@(D,D)
template <int D, typename WT>
__global__ __launch_bounds__(256) void proj_kernel(
    const float* __restrict__ x, const float* __restrict__ pw,
    const float* __restrict__ pb, float* __restrict__ xp)
{
    constexpr int NPB = 256 / D;             // nodes per block-iteration
    __shared__ WT    sw[D * D];
    __shared__ float s_in[NPB][D];
    const int tid = threadIdx.x;
    const int j   = tid % D;                 // output column
    const int sub = tid / D;                 // node slot
    for (int i = tid; i < D * D; i += 256) stw(sw[i], pw[i]);
    const float bias = pb[j];
    __syncthreads();
    for (int base = blockIdx.x * NPB; base < N_NODES; base += gridDim.x * NPB) {
        const int n = base + sub;
        const bool act = (n < N_NODES);
        if (act) s_in[sub][j] = x[(long long)n * D + j];
        __syncthreads();
        if (act) {
            float acc = bias;
            for (int i = 0; i < D; ++i)
                acc += s_in[sub][i] * ldw(sw[i * D + j]);
            xp[(long long)n * D + j] = fmaxf(acc, 0.0f);
        }
        __syncthreads();
    }
}

// msg[dst] += xp[src]  (atomic scatter, float4 per thread)
template <int D>
__global__ void scatter_kernel(const int* __restrict__ src, const int* __restrict__ dst,
                               const float* __restrict__ xp, float* __restrict__ msg)
{
    constexpr int CPE = D / 4;  // float4 chunks per edge
    long long idx = (long long)blockIdx.x * blockDim.x + threadIdx.x;
    if (idx >= (long long)N_EDGES * CPE) return;
    const int e = (int)(idx / CPE);
    const int c = (int)(idx % CPE);
    const int s = src[e], d = dst[e];
    const float4 v = *(const float4*)(xp + (long long)s * D + c * 4);
    float* mp = msg + (long long)d * D + c * 4;
    atomicAdd(mp + 0, v.x); atomicAdd(mp + 1, v.y);
    atomicAdd(mp + 2, v.z); atomicAdd(mp + 3, v.w);
}

// out = normalize((msg/max(deg,1)) @ wl + bl + x @ wr)   -> (N, 64)
template <int D, typename WT>
__global__ __launch_bounds__(256) void combine_kernel(
    const float* __restrict__ msg, const float* __restrict__ deg,
    const float* __restrict__ x, const float* __restrict__ wl,
    const float* __restrict__ bl, const float* __restrict__ wr,
    float* __restrict__ out)
{
    __shared__ WT    swl[D * HD], swr[D * HD];
    __shared__ float s_mean[4][D], s_x[4][D];
    const int tid  = threadIdx.x;
    const int wave = tid >> 6;
    const int lane = tid & 63;
    for (int i = tid; i < D * HD; i += 256) { stw(swl[i], wl[i]); stw(swr[i], wr[i]); }
    const float bias = bl[lane];
    __syncthreads();
    for (int base = blockIdx.x * 4; base < N_NODES; base += gridDim.x * 4) {
        const int n = base + wave;
        const bool act = (n < N_NODES);
        if (act) {
            const float inv = 1.0f / fmaxf(deg[n], 1.0f);
            for (int i = lane; i < D; i += 64) {
                s_mean[wave][i] = msg[(long long)n * D + i] * inv;
                s_x[wave][i]    = x[(long long)n * D + i];
            }
        }
        __syncthreads();
        if (act) {
            float acc = bias;
            for (int i = 0; i < D; ++i)
                acc += s_mean[wave][i] * ldw(swl[i * HD + lane])
                     + s_x[wave][i]    * ldw(swr[i * HD + lane]);
            float sq = acc * acc;
            #pragma unroll
            for (int off = 32; off > 0; off >>= 1) sq += __shfl_xor(sq, off, 64);
            const float nrm = fmaxf(sqrtf(sq), 1e-12f);
            out[(long long)n * HD + lane] = acc / nrm;
        }
        __syncthreads();
    }
}

// global atomics pooling: sum, count, max (encoded)
__global__ void pool_kernel(const float* __restrict__ x, const int* __restrict__ batch,
                            float* __restrict__ gsum, unsigned* __restrict__ gmax,
                            float* __restrict__ gcnt)
{
    long long idx = (long long)blockIdx.x * blockDim.x + threadIdx.x;
    if (idx >= (long long)N_NODES * HD) return;
    const int n = (int)(idx >> 6);
    const int k = (int)(idx & 63);
    const int g = batch[n];
    const float v = x[idx];
    atomicAdd(&gsum[g * HD + k], v);
    atomicMax(&gmax[g * HD + k], fenc(v));
    if (k == 0) atomicAdd(&gcnt[g], 1.0f);
}

__global__ void finalize_kernel(const float* __restrict__ gsum, const unsigned* __restrict__ gmax,
                                const float* __restrict__ gcnt, const float* __restrict__ post_w,
                                const float* __restrict__ post_b, float* __restrict__ out)
{
    const int g = blockIdx.x;    // 64 blocks × 64 threads (1 wave)
    const int k = threadIdx.x;
    const float cnt = gcnt[g];
    const float v = fdec(gmax[g * HD + k]) + gsum[g * HD + k] / cnt;
    const float w = post_w[k];
    float sq = v * v, dw = v * w;
    #pragma unroll
    for (int off = 32; off > 0; off >>= 1) {
        sq += __shfl_xor(sq, off, 64);
        dw += __shfl_xor(dw, off, 64);
    }
    if (k == 0) out[g] = dw / sqrtf(sq) + post_b[0];
}

extern "C" void kernel_launch(void* const* d_in, const int* in_sizes, int n_in,
                              void* d_out, int out_size, void* d_ws, size_t ws_size,
                              hipStream_t stream)
{
    const float* node_feat = (const float*)d_in[0];
    const float* cfg       = (const float*)d_in[1];
    const int*   opcode    = (const int*)  d_in[2];
    const int*   edge      = (const int*)  d_in[3];
    const int*   batch     = (const int*)  d_in[4];
    const float* op_emb    = (const float*)d_in[5];
    const float* lin_w     = (const float*)d_in[6];
    const float* lin_b     = (const float*)d_in[7];
    const float* post_w    = (const float*)d_in[8];
    const float* post_b    = (const float*)d_in[9];
    const float* pw[3] = {(const float*)d_in[10], (const float*)d_in[15], (const float*)d_in[20]};
    const float* pb[3] = {(const float*)d_in[11], (const float*)d_in[16], (const float*)d_in[21]};
    const float* wl[3] = {(const float*)d_in[12], (const float*)d_in[17], (const float*)d_in[22]};
    const float* bl[3] = {(const float*)d_in[13], (const float*)d_in[18], (const float*)d_in[23]};
    const float* wr[3] = {(const float*)d_in[14], (const float*)d_in[19], (const float*)d_in[24]};
    const int* srcp = edge;
    const int* dstp = edge + N_EDGES;

    // workspace layout (fp32 elements)
    float* ws   = (float*)d_ws;
    float* x_a  = ws;                       // N×128
    float* x_b  = ws + 12800000;            // N×128
    float* msg  = ws + 25600000;            // N×128
    float* deg  = ws + 38400000;            // N
    float* gsum = ws + 38500000;            // 64×64
    float* gcnt = ws + 38504096;            // 64
    unsigned* gmax = (unsigned*)(ws + 38504160);  // 64×64

    // zero deg + pooling accumulators (contiguous; gmax=0 decodes below any fenc(real))
    hipMemsetAsync(deg, 0, (size_t)(100000 + 4096 + 64 + 4096) * 4, stream);

    embed_linear<<<1024, 256, 0, stream>>>(node_feat, cfg, opcode, op_emb, lin_w, lin_b, x_a);
    deg_kernel<<<(N_EDGES + 255) / 256, 256, 0, stream>>>(dstp, deg);

    // ---- layer 0 (D = 128, bf16 LDS weights) ----
    proj_kernel<128, bf16><<<2048, 256, 0, stream>>>(x_a, pw[0], pb[0], x_b);
    hipMemsetAsync(msg, 0, (size_t)N_NODES * 128 * 4, stream);
    {
        long long tot = (long long)N_EDGES * (128 / 4);
        scatter_kernel<128><<<(int)((tot + 255) / 256), 256, 0, stream>>>(srcp, dstp, x_b, msg);
    }
    combine_kernel<128, bf16><<<2048, 256, 0, stream>>>(msg, deg, x_a, wl[0], bl[0], wr[0], x_b);

    // ---- layer 1 (D = 64, fp32 LDS weights) ----
    proj_kernel<64, float><<<2048, 256, 0, stream>>>(x_b, pw[1], pb[1], x_a);
    hipMemsetAsync(msg, 0, (size_t)N_NODES * 64 * 4, stream);
    {
        long long tot = (long long)N_EDGES * (64 / 4);
        scatter_kernel<64><<<(int)((tot + 255) / 256), 256, 0, stream>>>(srcp, dstp, x_a, msg);
    }
    combine_kernel<64, float><<<2048, 256, 0, stream>>>(msg, deg, x_b, wl[1], bl[1], wr[1], x_a);

    // ---- layer 2 (D = 64, fp32 LDS weights) ----
    proj_kernel<64, float><<<2048, 256, 0, stream>>>(x_a, pw[2], pb[2], x_b);
    hipMemsetAsync(msg, 0, (size_t)N_NODES * 64 * 4, stream);
    {
        long long tot = (long long)N_EDGES * (64 / 4);
        scatter_kernel<64><<<(int)((tot + 255) / 256), 256, 0, stream>>>(srcp, dstp, x_b, msg);
    }
    combine_kernel<64, float><<<2048, 256, 0, stream>>>(msg, deg, x_a, wl[2], bl[2], wr[2], x_b);

    // ---- pooling + head ----
    pool_kernel<<<(int)(((long long)N_NODES * 64 + 255) / 256), 256, 0, stream>>>(
        x_b, batch, gsum, gmax, gcnt);
    finalize_kernel<<<N_GRAPHS, 64, 0, stream>>>(gsum, gmax, gcnt, post_w, post_b,
                                                 (float*)d_out);
}

// Round 3
// 2666.126 us; speedup vs baseline: 2.8106x; 2.8106x over previous
//
#include <hip/hip_runtime.h>
#include <hip/hip_bf16.h>
#include <math.h>

typedef __hip_bfloat16 bf16;

#define N_NODES   100000
#define N_EDGES   1600000
#define N_GRAPHS  64
#define OP_EMB_D  32
#define NF_D      140
#define CFG_D     18
#define LIN_IN    190
#define LIN_OUT   128
#define HD        64
#define NB_SCAN   391   // ceil(N_NODES/256)

__device__ __forceinline__ float b2f(bf16 v) { return __bfloat162float(v); }

// weight-storage helpers: LDS weights may be fp32 or bf16
__device__ __forceinline__ float ldw(float v) { return v; }
__device__ __forceinline__ float ldw(bf16 v)  { return b2f(v); }
__device__ __forceinline__ void  stw(float& d, float v) { d = v; }
__device__ __forceinline__ void  stw(bf16& d, float v)  { d = __float2bfloat16(v); }

// monotone float<->uint encoding for atomicMax on floats
__device__ __forceinline__ unsigned fenc(float f) {
    unsigned u = __float_as_uint(f);
    return (u & 0x80000000u) ? ~u : (u | 0x80000000u);
}
__device__ __forceinline__ float fdec(unsigned u) {
    unsigned v = (u & 0x80000000u) ? (u & 0x7FFFFFFFu) : ~u;
    return __uint_as_float(v);
}

// ---------------- CSR build ----------------

__global__ void hist_kernel(const int* __restrict__ dst, int* __restrict__ cnt) {
    int e = blockIdx.x * blockDim.x + threadIdx.x;
    if (e < N_EDGES) atomicAdd(&cnt[dst[e]], 1);
}

__global__ __launch_bounds__(256) void blocksum_kernel(const int* __restrict__ cnt,
                                                       int* __restrict__ bsum) {
    const int tid = threadIdx.x, lane = tid & 63, wave = tid >> 6;
    int i = blockIdx.x * 256 + tid;
    int v = (i < N_NODES) ? cnt[i] : 0;
    #pragma unroll
    for (int off = 32; off > 0; off >>= 1) v += __shfl_xor(v, off, 64);
    __shared__ int wsum[4];
    if (lane == 0) wsum[wave] = v;
    __syncthreads();
    if (tid == 0) bsum[blockIdx.x] = wsum[0] + wsum[1] + wsum[2] + wsum[3];
}

__global__ __launch_bounds__(512) void scanbsum_kernel(int* __restrict__ bsum) {
    __shared__ int s[512];
    const int t = threadIdx.x;
    int v0 = (t < NB_SCAN) ? bsum[t] : 0;
    s[t] = v0;
    __syncthreads();
    for (int off = 1; off < 512; off <<= 1) {
        int add = (t >= off) ? s[t - off] : 0;
        __syncthreads();
        s[t] += add;
        __syncthreads();
    }
    if (t < NB_SCAN) bsum[t] = s[t] - v0;   // exclusive
}

// per-chunk exclusive scan + block offset -> row_start; cursor init (cnt aliased ok)
__global__ __launch_bounds__(256) void offsets_kernel(int* __restrict__ cnt,
                                                      const int* __restrict__ bsum,
                                                      int* __restrict__ row_start) {
    const int t = threadIdx.x;
    const int i = blockIdx.x * 256 + t;
    int v0 = (i < N_NODES) ? cnt[i] : 0;
    __shared__ int s[256];
    s[t] = v0;
    __syncthreads();
    for (int off = 1; off < 256; off <<= 1) {
        int add = (t >= off) ? s[t - off] : 0;
        __syncthreads();
        s[t] += add;
        __syncthreads();
    }
    const int excl = s[t] - v0 + bsum[blockIdx.x];
    if (i < N_NODES) {
        row_start[i] = excl;
        cnt[i] = excl;                 // becomes the fill cursor
    }
    if (i == N_NODES - 1) row_start[N_NODES] = excl + v0;  // == N_EDGES
}

__global__ void fill_kernel(const int* __restrict__ src, const int* __restrict__ dst,
                            int* __restrict__ cursor, int* __restrict__ nbr) {
    int e = blockIdx.x * blockDim.x + threadIdx.x;
    if (e < N_EDGES) {
        int slot = atomicAdd(&cursor[dst[e]], 1);
        nbr[slot] = src[e];
    }
}

// ---------------- dense layers ----------------

// x0 = relu(concat(node_feat, op_emb[opcode], cfg) @ lin_w + lin_b)  (N,190)@(190,128)
__global__ __launch_bounds__(256) void embed_linear(
    const float* __restrict__ node_feat, const float* __restrict__ cfg,
    const int* __restrict__ opcode, const float* __restrict__ op_emb,
    const float* __restrict__ lin_w, const float* __restrict__ lin_b,
    float* __restrict__ x_out)
{
    __shared__ bf16  sw[LIN_IN * LIN_OUT];   // 48640 B (bf16 storage)
    __shared__ float s_in[2][LIN_IN];
    const int tid = threadIdx.x;
    const int j   = tid & 127;               // output column
    const int sub = tid >> 7;                // node slot 0/1
    for (int i = tid; i < LIN_IN * LIN_OUT; i += 256) stw(sw[i], lin_w[i]);
    const float bias = lin_b[j];
    __syncthreads();
    for (int base = blockIdx.x * 2; base < N_NODES; base += gridDim.x * 2) {
        const int n = base + sub;
        const bool act = (n < N_NODES);
        if (act) {
            for (int i = j; i < NF_D; i += 128) s_in[sub][i] = node_feat[(long long)n * NF_D + i];
            const int op = opcode[n];
            if (j < OP_EMB_D) s_in[sub][NF_D + j] = op_emb[op * OP_EMB_D + j];
            if (j < CFG_D)    s_in[sub][NF_D + OP_EMB_D + j] = cfg[(long long)n * CFG_D + j];
        }
        __syncthreads();
        if (act) {
            float acc = bias;
            #pragma unroll 2
            for (int i = 0; i < LIN_IN; ++i)
                acc += s_in[sub][i] * b2f(sw[i * LIN_OUT + j]);
            x_out[(long long)n * LIN_OUT + j] = fmaxf(acc, 0.0f);
        }
        __syncthreads();
    }
}

// xp = relu(x @ pw + pb)   (N,D)@(D,D)
template <int D, typename WT>
__global__ __launch_bounds__(256) void proj_kernel(
    const float* __restrict__ x, const float* __restrict__ pw,
    const float* __restrict__ pb, float* __restrict__ xp)
{
    constexpr int NPB = 256 / D;             // nodes per block-iteration
    __shared__ WT    sw[D * D];
    __shared__ float s_in[NPB][D];
    const int tid = threadIdx.x;
    const int j   = tid % D;                 // output column
    const int sub = tid / D;                 // node slot
    for (int i = tid; i < D * D; i += 256) stw(sw[i], pw[i]);
    const float bias = pb[j];
    __syncthreads();
    for (int base = blockIdx.x * NPB; base < N_NODES; base += gridDim.x * NPB) {
        const int n = base + sub;
        const bool act = (n < N_NODES);
        if (act) s_in[sub][j] = x[(long long)n * D + j];
        __syncthreads();
        if (act) {
            float acc = bias;
            for (int i = 0; i < D; ++i)
                acc += s_in[sub][i] * ldw(sw[i * D + j]);
            xp[(long long)n * D + j] = fmaxf(acc, 0.0f);
        }
        __syncthreads();
    }
}

// fused gather + combine: out = normalize(mean_{src in CSR[n]}(xp[src]) @ wl + bl + x @ wr)
// one wave per node; neighbor ids fetched 64-wide then shfl-broadcast
template <int D, typename WT>
__global__ __launch_bounds__(256) void gather_combine(
    const int* __restrict__ row_start, const int* __restrict__ nbr,
    const float* __restrict__ xp, const float* __restrict__ x,
    const float* __restrict__ wl, const float* __restrict__ bl,
    const float* __restrict__ wr, float* __restrict__ out)
{
    __shared__ WT    swl[D * HD], swr[D * HD];
    __shared__ float s_mean[4][D], s_x[4][D];
    const int tid  = threadIdx.x;
    const int wave = tid >> 6;
    const int lane = tid & 63;
    for (int i = tid; i < D * HD; i += 256) { stw(swl[i], wl[i]); stw(swr[i], wr[i]); }
    const float bias = bl[lane];
    __syncthreads();
    for (int base = blockIdx.x * 4; base < N_NODES; base += gridDim.x * 4) {
        const int n = base + wave;
        if (n < N_NODES) {
            const int rs = row_start[n], re = row_start[n + 1];
            float m0 = 0.0f, m1 = 0.0f;
            for (int eb = rs; eb < re; eb += 64) {
                const int m  = min(64, re - eb);
                const int my = (eb + lane < re) ? nbr[eb + lane] : 0;
                for (int j2 = 0; j2 < m; ++j2) {
                    const int s = __shfl(my, j2, 64);
                    m0 += xp[(long long)s * D + lane];
                    if (D == 128) m1 += xp[(long long)s * D + 64 + lane];
                }
            }
            const float inv = 1.0f / fmaxf((float)(re - rs), 1.0f);
            s_mean[wave][lane] = m0 * inv;
            s_x[wave][lane]    = x[(long long)n * D + lane];
            if (D == 128) {
                s_mean[wave][64 + lane] = m1 * inv;
                s_x[wave][64 + lane]    = x[(long long)n * D + 64 + lane];
            }
            // per-wave LDS slot: intra-wave ordering is sufficient
            float acc = bias;
            for (int i = 0; i < D; ++i)
                acc += s_mean[wave][i] * ldw(swl[i * HD + lane])
                     + s_x[wave][i]    * ldw(swr[i * HD + lane]);
            float sq = acc * acc;
            #pragma unroll
            for (int off = 32; off > 0; off >>= 1) sq += __shfl_xor(sq, off, 64);
            const float nrm = fmaxf(sqrtf(sq), 1e-12f);
            out[(long long)n * HD + lane] = acc / nrm;
        }
    }
}

// ---------------- pooling + head ----------------

__global__ void pool_kernel(const float* __restrict__ x, const int* __restrict__ batch,
                            float* __restrict__ gsum, unsigned* __restrict__ gmax,
                            float* __restrict__ gcnt)
{
    long long idx = (long long)blockIdx.x * blockDim.x + threadIdx.x;
    if (idx >= (long long)N_NODES * HD) return;
    const int n = (int)(idx >> 6);
    const int k = (int)(idx & 63);
    const int g = batch[n];
    const float v = x[idx];
    atomicAdd(&gsum[g * HD + k], v);
    atomicMax(&gmax[g * HD + k], fenc(v));
    if (k == 0) atomicAdd(&gcnt[g], 1.0f);
}

__global__ void finalize_kernel(const float* __restrict__ gsum, const unsigned* __restrict__ gmax,
                                const float* __restrict__ gcnt, const float* __restrict__ post_w,
                                const float* __restrict__ post_b, float* __restrict__ out)
{
    const int g = blockIdx.x;    // 64 blocks × 64 threads (1 wave)
    const int k = threadIdx.x;
    const float cnt = gcnt[g];
    const float v = fdec(gmax[g * HD + k]) + gsum[g * HD + k] / cnt;
    const float w = post_w[k];
    float sq = v * v, dw = v * w;
    #pragma unroll
    for (int off = 32; off > 0; off >>= 1) {
        sq += __shfl_xor(sq, off, 64);
        dw += __shfl_xor(dw, off, 64);
    }
    if (k == 0) out[g] = dw / sqrtf(sq) + post_b[0];
}

extern "C" void kernel_launch(void* const* d_in, const int* in_sizes, int n_in,
                              void* d_out, int out_size, void* d_ws, size_t ws_size,
                              hipStream_t stream)
{
    const float* node_feat = (const float*)d_in[0];
    const float* cfg       = (const float*)d_in[1];
    const int*   opcode    = (const int*)  d_in[2];
    const int*   edge      = (const int*)  d_in[3];
    const int*   batch     = (const int*)  d_in[4];
    const float* op_emb    = (const float*)d_in[5];
    const float* lin_w     = (const float*)d_in[6];
    const float* lin_b     = (const float*)d_in[7];
    const float* post_w    = (const float*)d_in[8];
    const float* post_b    = (const float*)d_in[9];
    const float* pw[3] = {(const float*)d_in[10], (const float*)d_in[15], (const float*)d_in[20]};
    const float* pb[3] = {(const float*)d_in[11], (const float*)d_in[16], (const float*)d_in[21]};
    const float* wl[3] = {(const float*)d_in[12], (const float*)d_in[17], (const float*)d_in[22]};
    const float* bl[3] = {(const float*)d_in[13], (const float*)d_in[18], (const float*)d_in[23]};
    const float* wr[3] = {(const float*)d_in[14], (const float*)d_in[19], (const float*)d_in[24]};
    const int* srcp = edge;
    const int* dstp = edge + N_EDGES;

    // workspace layout (4-byte elements)
    float* ws   = (float*)d_ws;
    float* A    = ws;                         // N×128
    float* B    = ws + 12800000;              // N×128
    float* C    = ws + 25600000;              // N×64
    int*   nbr  = (int*)(ws + 32000000);      // N_EDGES
    int*   row_start = (int*)(ws + 33600000); // N+1
    int*   cnt  = (int*)(ws + 33700064);      // N (counts, then fill cursor)
    float* gsum = ws + 33800064;              // 64×64
    float* gcnt = ws + 33804160;              // 64
    unsigned* gmax = (unsigned*)(ws + 33804224); // 64×64
    int*   bsum = (int*)(ws + 33808320);      // 512

    // zero cnt + pooling accumulators (contiguous region; fenc(0)=min)
    hipMemsetAsync(cnt, 0, (size_t)(100000 + 4096 + 64 + 4096) * 4, stream);

    // ---- CSR build (by dst) ----
    hist_kernel<<<(N_EDGES + 255) / 256, 256, 0, stream>>>(dstp, cnt);
    blocksum_kernel<<<NB_SCAN, 256, 0, stream>>>(cnt, bsum);
    scanbsum_kernel<<<1, 512, 0, stream>>>(bsum);
    offsets_kernel<<<NB_SCAN, 256, 0, stream>>>(cnt, bsum, row_start);
    fill_kernel<<<(N_EDGES + 255) / 256, 256, 0, stream>>>(srcp, dstp, cnt, nbr);

    // ---- embed ----
    embed_linear<<<1024, 256, 0, stream>>>(node_feat, cfg, opcode, op_emb, lin_w, lin_b, A);

    // ---- layer 0 (D = 128, bf16 LDS weights) ----
    proj_kernel<128, bf16><<<2048, 256, 0, stream>>>(A, pw[0], pb[0], B);
    gather_combine<128, bf16><<<2048, 256, 0, stream>>>(row_start, nbr, B, A,
                                                        wl[0], bl[0], wr[0], C);

    // ---- layer 1 (D = 64, fp32 LDS weights) ----
    proj_kernel<64, float><<<2048, 256, 0, stream>>>(C, pw[1], pb[1], A);
    gather_combine<64, float><<<2048, 256, 0, stream>>>(row_start, nbr, A, C,
                                                        wl[1], bl[1], wr[1], B);

    // ---- layer 2 (D = 64, fp32 LDS weights) ----
    proj_kernel<64, float><<<2048, 256, 0, stream>>>(B, pw[2], pb[2], A);
    gather_combine<64, float><<<2048, 256, 0, stream>>>(row_start, nbr, A, B,
                                                        wl[2], bl[2], wr[2], C);

    // ---- pooling + head ----
    pool_kernel<<<(int)(((long long)N_NODES * 64 + 255) / 256), 256, 0, stream>>>(
        C, batch, gsum, gmax, gcnt);
    finalize_kernel<<<N_GRAPHS, 64, 0, stream>>>(gsum, gmax, gcnt, post_w, post_b,
                                                 (float*)d_out);
}

// Round 4
// 1542.815 us; speedup vs baseline: 4.8570x; 1.7281x over previous
//
#include <hip/hip_runtime.h>
#include <hip/hip_bf16.h>
#include <math.h>

#define N_NODES   100000
#define N_EDGES   1600000
#define N_GRAPHS  64
#define NF_D      140
#define OP_EMB_D  32
#define CFG_D     18
#define K_EMB     192     // 190 zero-padded to 192
#define NB_SCAN   391     // ceil(N_NODES/256)

// monotone float<->uint encoding for atomicMax on floats
__device__ __forceinline__ unsigned fenc(float f) {
    unsigned u = __float_as_uint(f);
    return (u & 0x80000000u) ? ~u : (u | 0x80000000u);
}
__device__ __forceinline__ float fdec(unsigned u) {
    unsigned v = (u & 0x80000000u) ? (u & 0x7FFFFFFFu) : ~u;
    return __uint_as_float(v);
}
__device__ __forceinline__ float rdlane(float v, int l) {
    return __uint_as_float(__builtin_amdgcn_readlane(__float_as_uint(v), l));
}

// ---------------- CSR build ----------------

__global__ void hist_kernel(const int* __restrict__ dst, int* __restrict__ cnt) {
    int e = blockIdx.x * blockDim.x + threadIdx.x;
    if (e < N_EDGES) atomicAdd(&cnt[dst[e]], 1);
}

__global__ __launch_bounds__(256) void blocksum_kernel(const int* __restrict__ cnt,
                                                       int* __restrict__ bsum) {
    const int tid = threadIdx.x, lane = tid & 63, wave = tid >> 6;
    int i = blockIdx.x * 256 + tid;
    int v = (i < N_NODES) ? cnt[i] : 0;
    #pragma unroll
    for (int off = 32; off > 0; off >>= 1) v += __shfl_xor(v, off, 64);
    __shared__ int wsum[4];
    if (lane == 0) wsum[wave] = v;
    __syncthreads();
    if (tid == 0) bsum[blockIdx.x] = wsum[0] + wsum[1] + wsum[2] + wsum[3];
}

__global__ __launch_bounds__(512) void scanbsum_kernel(int* __restrict__ bsum) {
    __shared__ int s[512];
    const int t = threadIdx.x;
    int v0 = (t < NB_SCAN) ? bsum[t] : 0;
    s[t] = v0;
    __syncthreads();
    for (int off = 1; off < 512; off <<= 1) {
        int add = (t >= off) ? s[t - off] : 0;
        __syncthreads();
        s[t] += add;
        __syncthreads();
    }
    if (t < NB_SCAN) bsum[t] = s[t] - v0;   // exclusive
}

__global__ __launch_bounds__(256) void offsets_kernel(int* __restrict__ cnt,
                                                      const int* __restrict__ bsum,
                                                      int* __restrict__ row_start) {
    const int t = threadIdx.x;
    const int i = blockIdx.x * 256 + t;
    int v0 = (i < N_NODES) ? cnt[i] : 0;
    __shared__ int s[256];
    s[t] = v0;
    __syncthreads();
    for (int off = 1; off < 256; off <<= 1) {
        int add = (t >= off) ? s[t - off] : 0;
        __syncthreads();
        s[t] += add;
        __syncthreads();
    }
    const int excl = s[t] - v0 + bsum[blockIdx.x];
    if (i < N_NODES) {
        row_start[i] = excl;
        cnt[i] = excl;                 // becomes the fill cursor
    }
    if (i == N_NODES - 1) row_start[N_NODES] = excl + v0;  // == N_EDGES
}

__global__ void fill_kernel(const int* __restrict__ src, const int* __restrict__ dst,
                            int* __restrict__ cursor, int* __restrict__ nbr) {
    int e = blockIdx.x * blockDim.x + threadIdx.x;
    if (e < N_EDGES) {
        int slot = atomicAdd(&cursor[dst[e]], 1);
        nbr[slot] = src[e];
    }
}

// ---------------- input concat + weight pad ----------------

// X0[n][0:140]=node_feat, [140:172]=op_emb[op], [172:190]=cfg, [190:192]=0; stride 192
__global__ __launch_bounds__(256) void concat_kernel(
    const float* __restrict__ node_feat, const float* __restrict__ cfg,
    const int* __restrict__ opcode, const float* __restrict__ op_emb,
    float* __restrict__ x0)
{
    const long long total = (long long)N_NODES * 96;   // float2 units
    for (long long idx = (long long)blockIdx.x * blockDim.x + threadIdx.x;
         idx < total; idx += (long long)gridDim.x * blockDim.x) {
        const int n  = (int)(idx / 96);
        const int c  = 2 * (int)(idx % 96);
        float2 v;
        if (c < NF_D) {
            v = *(const float2*)(node_feat + (long long)n * NF_D + c);
        } else if (c < NF_D + OP_EMB_D) {
            const int op = opcode[n];
            v = *(const float2*)(op_emb + op * OP_EMB_D + (c - NF_D));
        } else if (c < 190) {
            v = *(const float2*)(cfg + (long long)n * CFG_D + (c - NF_D - OP_EMB_D));
        } else {
            v.x = 0.f; v.y = 0.f;
        }
        *(float2*)(x0 + (long long)n * K_EMB + c) = v;
    }
}

// lin_w (190x128) -> wpad (192x128), rows 190,191 zero
__global__ void wpad_kernel(const float* __restrict__ w, float* __restrict__ wp) {
    int i = blockIdx.x * blockDim.x + threadIdx.x;
    if (i < K_EMB * 128) wp[i] = (i < 190 * 128) ? w[i] : 0.f;
}

// ---------------- lane-per-node GEMM:  out = act(x @ w + b) ----------------
// wave = 64-node tile, lane = node. x: N x SX (K<=SX used), w: K x M row-major.
// Weights indexed wave-uniformly -> scalar loads; x staged to LDS, b128 reads.
template <int M, bool BIAS, bool RELU>
__global__ __launch_bounds__(256) void gemm_kernel(
    const float* __restrict__ x, int SX, int K,
    const float* __restrict__ w, const float* __restrict__ b,
    float* __restrict__ out, int N)
{
    __shared__ float sx[4][64][36];          // 36-float rows: b128 at conflict floor
    const int tid = threadIdx.x, wave = tid >> 6, lane = tid & 63;
    const int r8 = lane >> 3;                // staging row-sub 0..7
    const int c4 = lane & 7;                 // staging f4-col 0..7
    const int ntiles = (N + 63) >> 6;
    for (int tile = blockIdx.x * 4 + wave; tile < ntiles; tile += gridDim.x * 4) {
        const int base = tile << 6;
        #pragma unroll
        for (int jh = 0; jh < M / 64; ++jh) {
            float acc[64];
            #pragma unroll
            for (int j = 0; j < 64; ++j) acc[j] = BIAS ? b[jh * 64 + j] : 0.f;
            for (int kc = 0; kc < K; kc += 32) {
                #pragma unroll
                for (int rt = 0; rt < 8; ++rt) {        // stage 64 rows x 32 cols
                    int row = base + rt * 8 + r8;
                    if (row >= N) row = N - 1;
                    float4 v = *(const float4*)(x + (long long)row * SX + kc + c4 * 4);
                    *(float4*)(&sx[wave][rt * 8 + r8][c4 * 4]) = v;
                }
                // wave-local staging: in-order DS pipe + compiler waitcnt suffice
                #pragma unroll 2
                for (int i4 = 0; i4 < 8; ++i4) {
                    float4 xv = *(const float4*)(&sx[wave][lane][i4 * 4]);
                    const float* wrow = w + (long long)(kc + i4 * 4) * M + jh * 64;
                    #pragma unroll
                    for (int q = 0; q < 4; ++q) {
                        const float xq = (q == 0) ? xv.x : (q == 1) ? xv.y
                                       : (q == 2) ? xv.z : xv.w;
                        #pragma unroll
                        for (int j = 0; j < 64; ++j)
                            acc[j] = fmaf(xq, wrow[q * M + j], acc[j]);
                    }
                }
            }
            const int n = base + lane;
            if (n < N) {
                float* orow = out + (long long)n * M + jh * 64;
                #pragma unroll
                for (int j4 = 0; j4 < 16; ++j4) {
                    float4 v;
                    v.x = acc[j4 * 4 + 0]; v.y = acc[j4 * 4 + 1];
                    v.z = acc[j4 * 4 + 2]; v.w = acc[j4 * 4 + 3];
                    if (RELU) {
                        v.x = fmaxf(v.x, 0.f); v.y = fmaxf(v.y, 0.f);
                        v.z = fmaxf(v.z, 0.f); v.w = fmaxf(v.w, 0.f);
                    }
                    *(float4*)(orow + j4 * 4) = v;
                }
            }
        }
    }
}

// ---------------- fused gather + root-term + normalize ----------------
// out[n] = normalize( gather_mean(yp)[n] + x[n] @ wr + bl ),  yp = xp@wl (N x 64)
// wave per node; wr column `lane` register-resident; x broadcast via readlane.
template <int D>
__global__ __launch_bounds__(256) void combine_kernel(
    const int* __restrict__ row_start, const int* __restrict__ nbr,
    const float* __restrict__ yp, const float* __restrict__ x,
    const float* __restrict__ wr, const float* __restrict__ bl,
    float* __restrict__ out)
{
    const int tid = threadIdx.x, wave = tid >> 6, lane = tid & 63;
    float wrc[D];
    #pragma unroll
    for (int i = 0; i < D; ++i) wrc[i] = wr[i * 64 + lane];   // coalesced per i
    const float bias = bl[lane];
    for (int n = blockIdx.x * 4 + wave; n < N_NODES; n += gridDim.x * 4) {
        const int rs = row_start[n], re = row_start[n + 1];
        float m = 0.f;
        for (int eb = rs; eb < re; eb += 64) {
            const int cnt = min(64, re - eb);
            const int my = (eb + lane < re) ? nbr[eb + lane] : 0;
            for (int j2 = 0; j2 < cnt; ++j2) {
                const int s = __shfl(my, j2, 64);
                m += yp[(long long)s * 64 + lane];
            }
        }
        float acc = bias + m / fmaxf((float)(re - rs), 1.0f);
        const float xv0 = x[(long long)n * D + lane];
        #pragma unroll
        for (int i = 0; i < 64; ++i) acc = fmaf(rdlane(xv0, i), wrc[i], acc);
        if (D == 128) {
            const float xv1 = x[(long long)n * D + 64 + lane];
            #pragma unroll
            for (int i = 0; i < 64; ++i) acc = fmaf(rdlane(xv1, i), wrc[64 + i], acc);
        }
        float sq = acc * acc;
        #pragma unroll
        for (int off = 32; off > 0; off >>= 1) sq += __shfl_xor(sq, off, 64);
        out[(long long)n * 64 + lane] = acc / fmaxf(sqrtf(sq), 1e-12f);
    }
}

// ---------------- pooling (block pre-reduction) + head ----------------

__global__ __launch_bounds__(256) void pool_kernel(
    const float* __restrict__ x, const int* __restrict__ batch,
    float* __restrict__ gsum, unsigned* __restrict__ gmax, float* __restrict__ gcnt)
{
    __shared__ float    lsum[2][64];
    __shared__ unsigned lmax[2][64];
    __shared__ int      lcnt[2];
    const int tid = threadIdx.x, wave = tid >> 6, lane = tid & 63;
    if (tid < 128) { lsum[tid >> 6][tid & 63] = 0.f; lmax[tid >> 6][tid & 63] = 0u; }
    if (tid < 2) lcnt[tid] = 0;
    __syncthreads();
    const int base = blockIdx.x * 256;
    const int g0 = batch[base];
    float a0 = 0.f, a1 = 0.f, x0 = -INFINITY, x1 = -INFINITY;
    int c0 = 0, c1 = 0;
    for (int nn = 0; nn < 64; ++nn) {
        const int n = base + wave * 64 + nn;
        if (n >= N_NODES) break;
        const float v = x[(long long)n * 64 + lane];
        const int slot = batch[n] - g0;
        if (slot == 0)      { a0 += v; x0 = fmaxf(x0, v); c0++; }
        else if (slot == 1) { a1 += v; x1 = fmaxf(x1, v); c1++; }
        else {  // robustness fallback (non-contiguous batch)
            const int g = g0 + slot;
            atomicAdd(&gsum[g * 64 + lane], v);
            atomicMax(&gmax[g * 64 + lane], fenc(v));
            if (lane == 0) atomicAdd(&gcnt[g], 1.f);
        }
    }
    if (c0) { atomicAdd(&lsum[0][lane], a0); atomicMax(&lmax[0][lane], fenc(x0));
              if (lane == 0) atomicAdd(&lcnt[0], c0); }
    if (c1) { atomicAdd(&lsum[1][lane], a1); atomicMax(&lmax[1][lane], fenc(x1));
              if (lane == 0) atomicAdd(&lcnt[1], c1); }
    __syncthreads();
    if (tid < 128) {
        const int slot = tid >> 6, k = tid & 63;
        if (lcnt[slot] > 0) {
            const int g = g0 + slot;
            atomicAdd(&gsum[g * 64 + k], lsum[slot][k]);
            atomicMax(&gmax[g * 64 + k], lmax[slot][k]);
            if (k == 0) atomicAdd(&gcnt[g], (float)lcnt[slot]);
        }
    }
}

__global__ void finalize_kernel(const float* __restrict__ gsum, const unsigned* __restrict__ gmax,
                                const float* __restrict__ gcnt, const float* __restrict__ post_w,
                                const float* __restrict__ post_b, float* __restrict__ out)
{
    const int g = blockIdx.x;    // 64 blocks x 64 threads (1 wave)
    const int k = threadIdx.x;
    const float cnt = gcnt[g];
    const float v = fdec(gmax[g * 64 + k]) + gsum[g * 64 + k] / cnt;
    const float w = post_w[k];
    float sq = v * v, dw = v * w;
    #pragma unroll
    for (int off = 32; off > 0; off >>= 1) {
        sq += __shfl_xor(sq, off, 64);
        dw += __shfl_xor(dw, off, 64);
    }
    if (k == 0) out[g] = dw / sqrtf(sq) + post_b[0];
}

extern "C" void kernel_launch(void* const* d_in, const int* in_sizes, int n_in,
                              void* d_out, int out_size, void* d_ws, size_t ws_size,
                              hipStream_t stream)
{
    const float* node_feat = (const float*)d_in[0];
    const float* cfg       = (const float*)d_in[1];
    const int*   opcode    = (const int*)  d_in[2];
    const int*   edge      = (const int*)  d_in[3];
    const int*   batch     = (const int*)  d_in[4];
    const float* op_emb    = (const float*)d_in[5];
    const float* lin_w     = (const float*)d_in[6];
    const float* lin_b     = (const float*)d_in[7];
    const float* post_w    = (const float*)d_in[8];
    const float* post_b    = (const float*)d_in[9];
    const float* pw[3] = {(const float*)d_in[10], (const float*)d_in[15], (const float*)d_in[20]};
    const float* pb[3] = {(const float*)d_in[11], (const float*)d_in[16], (const float*)d_in[21]};
    const float* wl[3] = {(const float*)d_in[12], (const float*)d_in[17], (const float*)d_in[22]};
    const float* bl[3] = {(const float*)d_in[13], (const float*)d_in[18], (const float*)d_in[23]};
    const float* wr[3] = {(const float*)d_in[14], (const float*)d_in[19], (const float*)d_in[24]};
    const int* srcp = edge;
    const int* dstp = edge + N_EDGES;

    // workspace layout (fp32 elements), ~135 MB total
    float* ws   = (float*)d_ws;
    float* A    = ws;                          // 12.8M: embed out (N x 128); later C2 @ +0... (see below)
    float* R1   = ws + 12800000;               // 19.2M: X0 (N x 192); later xp/yp/C slots
    int*   nbr       = (int*)(ws + 32000000);  // 1.6M
    int*   row_start = (int*)(ws + 33600000);  // N+1
    int*   cnt       = (int*)(ws + 33700064);  // N (counts -> fill cursor)
    int*   bsum      = (int*)(ws + 33800064);  // 512
    float* wpad      = ws + 33800576;          // 192*128
    float* gsum      = ws + 33825152;          // 64*64
    float* gcnt      = ws + 33829248;          // 64
    unsigned* gmax   = (unsigned*)(ws + 33829312); // 64*64

    // buffer lifetimes (all aliases into A / R1):
    float* X0  = R1;                  // alive: concat -> embed
    float* xp0 = R1;                  // N x 128, alive: proj0 -> yp0
    float* yp  = R1 + 12800000;       // N x 64, reused all 3 layers
    float* C1  = R1;                  // N x 64, overwrites dead xp0 at combine0
    float* xp64 = R1 + 6400000;       // N x 64, layers 1/2 proj out
    float* C2  = A;                   // overwrites dead embed-out
    float* C3  = R1 + 12800000 - 6400000 + 0; // placed below; see note
    // C3: C1 slot is dead after combine1's x-read... C1 is read by proj1/yp-chain AND combine1.
    // After combine1 completes, C1 dead -> C3 reuses C1 slot:
    C3 = R1;

    hipMemsetAsync(cnt, 0, (size_t)N_NODES * 4, stream);
    hipMemsetAsync(gsum, 0, (size_t)(4096 + 64 + 4096) * 4, stream);

    // ---- CSR build (by dst) ----
    hist_kernel<<<(N_EDGES + 255) / 256, 256, 0, stream>>>(dstp, cnt);
    blocksum_kernel<<<NB_SCAN, 256, 0, stream>>>(cnt, bsum);
    scanbsum_kernel<<<1, 512, 0, stream>>>(bsum);
    offsets_kernel<<<NB_SCAN, 256, 0, stream>>>(cnt, bsum, row_start);
    fill_kernel<<<(N_EDGES + 255) / 256, 256, 0, stream>>>(srcp, dstp, cnt, nbr);

    // ---- embed: X0 = concat; A = relu(X0 @ wpad + lin_b) ----
    concat_kernel<<<4096, 256, 0, stream>>>(node_feat, cfg, opcode, op_emb, X0);
    wpad_kernel<<<(K_EMB * 128 + 255) / 256, 256, 0, stream>>>(lin_w, wpad);
    gemm_kernel<128, true, true><<<391, 256, 0, stream>>>(X0, K_EMB, K_EMB, wpad, lin_b, A, N_NODES);

    // ---- layer 0 (D=128) ----
    gemm_kernel<128, true, true ><<<391, 256, 0, stream>>>(A, 128, 128, pw[0], pb[0], xp0, N_NODES);
    gemm_kernel< 64, false, false><<<391, 256, 0, stream>>>(xp0, 128, 128, wl[0], nullptr, yp, N_NODES);
    combine_kernel<128><<<2048, 256, 0, stream>>>(row_start, nbr, yp, A, wr[0], bl[0], C1);

    // ---- layer 1 (D=64) ----
    gemm_kernel< 64, true, true ><<<391, 256, 0, stream>>>(C1, 64, 64, pw[1], pb[1], xp64, N_NODES);
    gemm_kernel< 64, false, false><<<391, 256, 0, stream>>>(xp64, 64, 64, wl[1], nullptr, yp, N_NODES);
    combine_kernel<64><<<2048, 256, 0, stream>>>(row_start, nbr, yp, C1, wr[1], bl[1], C2);

    // ---- layer 2 (D=64) ----
    gemm_kernel< 64, true, true ><<<391, 256, 0, stream>>>(C2, 64, 64, pw[2], pb[2], xp64, N_NODES);
    gemm_kernel< 64, false, false><<<391, 256, 0, stream>>>(xp64, 64, 64, wl[2], nullptr, yp, N_NODES);
    combine_kernel<64><<<2048, 256, 0, stream>>>(row_start, nbr, yp, C2, wr[2], bl[2], C3);

    // ---- pooling + head ----
    pool_kernel<<<NB_SCAN, 256, 0, stream>>>(C3, batch, gsum, gmax, gcnt);
    finalize_kernel<<<N_GRAPHS, 64, 0, stream>>>(gsum, gmax, gcnt, post_w, post_b,
                                                 (float*)d_out);
}